// Round 5
// baseline (1721.920 us; speedup 1.0000x reference)
//
#include <hip/hip_runtime.h>
#include <hip/hip_bf16.h>

#define N_NODES   100000
#define N_EDGES   1600000
#define FDIM      128
#define N_GRAPHS  1024
#define N_CLASSES 32
#define SCAN_BLK  1024
#define M_PAD     100032            // padded rows for 64-row GEMM tiles
#define CHUNK     1563              // sources per pool chunk (64*1563 >= N)
#define NCHUNK    64

typedef __attribute__((ext_vector_type(8))) short short8v;
typedef __attribute__((ext_vector_type(4))) float f32x4;

__device__ __forceinline__ float bflo(unsigned u){ union{unsigned i; float f;} c; c.i = u << 16; return c.f; }
__device__ __forceinline__ float bfhi(unsigned u){ union{unsigned i; float f;} c; c.i = u & 0xffff0000u; return c.f; }
__device__ __forceinline__ unsigned short f2bf(float f){
    union{float f; unsigned u;} c{f};
    return (unsigned short)((c.u + 0x7fffu + ((c.u >> 16) & 1u)) >> 16);
}
__device__ __forceinline__ unsigned packbf2(float a, float b){
    return (unsigned)f2bf(a) | ((unsigned)f2bf(b) << 16);
}
// pack graph id into low 10 mantissa bits of w (w in (0,1], normal): rel err <= 2^-12
__device__ __forceinline__ int packgw(float w, int g){
    return (__float_as_int(w) & ~1023) | g;
}

__device__ __forceinline__ void fma8(float* acc, float w, uint4 u) {
    acc[0] += w * bflo(u.x); acc[1] += w * bfhi(u.x);
    acc[2] += w * bflo(u.y); acc[3] += w * bfhi(u.y);
    acc[4] += w * bflo(u.z); acc[5] += w * bfhi(u.z);
    acc[6] += w * bflo(u.w); acc[7] += w * bfhi(u.w);
}

// ---------------------------------------------------------------------------
// fp32 -> packed bf16x2 dense rows (n2 = number of float PAIRS)
__global__ void k_f2bf(const float* __restrict__ in, unsigned* __restrict__ out, int n2) {
    int i = blockIdx.x * blockDim.x + threadIdx.x;
    if (i < n2) {
        float2 v = ((const float2*)in)[i];
        out[i] = packbf2(v.x, v.y);
    }
}

// W1 [k][n] fp32 -> Wt [n][k] bf16
__global__ void k_wt(const float* __restrict__ W, unsigned short* __restrict__ Wt) {
    int i = blockIdx.x * blockDim.x + threadIdx.x;   // 16384
    int k = i >> 7, n = i & 127;
    Wt[n * 128 + k] = f2bf(W[i]);
}

// ---------------------------------------------------------------------------
__global__ void k_count(const int* __restrict__ idx, int* __restrict__ deg, int E) {
    int i = blockIdx.x * blockDim.x + threadIdx.x;
    if (i < E) atomicAdd(&deg[idx[i]], 1);
}

__global__ void k_dinv(const int* __restrict__ indeg, float* __restrict__ dinv, int n) {
    int i = blockIdx.x * blockDim.x + threadIdx.x;
    if (i < n) dinv[i] = rsqrtf((float)(indeg[i] + 1));
}

__global__ void k_p1(int* __restrict__ a, int n) {   // a[i] += 1 (self slot)
    int i = blockIdx.x * blockDim.x + threadIdx.x;
    if (i < n) a[i] += 1;
}

__global__ void k_scan1(const int* __restrict__ in, int* __restrict__ out,
                        int* __restrict__ bsums, int n) {
    __shared__ int lds[256];
    int blk = blockIdx.x, t = threadIdx.x;
    int base = blk * SCAN_BLK + t * 4;
    int v[4];
#pragma unroll
    for (int i = 0; i < 4; ++i) v[i] = (base + i < n) ? in[base + i] : 0;
    int local = v[0] + v[1] + v[2] + v[3];
    lds[t] = local;
    __syncthreads();
    for (int off = 1; off < 256; off <<= 1) {
        int x = lds[t];
        int y = (t >= off) ? lds[t - off] : 0;
        __syncthreads();
        lds[t] = x + y;
        __syncthreads();
    }
    int excl = lds[t] - local;
    if (t == 255) bsums[blk] = lds[255];
    int run = excl;
#pragma unroll
    for (int i = 0; i < 4; ++i) {
        if (base + i < n) { out[base + i] = run; run += v[i]; }
    }
}

__global__ void k_scan2(int* __restrict__ bsums, int nb) {
    __shared__ int lds[256];
    int t = threadIdx.x;
    int orig = (t < nb) ? bsums[t] : 0;
    lds[t] = orig;
    __syncthreads();
    for (int off = 1; off < 256; off <<= 1) {
        int x = lds[t];
        int y = (t >= off) ? lds[t - off] : 0;
        __syncthreads();
        lds[t] = x + y;
        __syncthreads();
    }
    if (t < nb) bsums[t] = lds[t] - orig;
}

__global__ void k_scan3(int* __restrict__ rp, const int* __restrict__ boffs, int n, int TOT) {
    int i = blockIdx.x * blockDim.x + threadIdx.x;
    if (i < n) rp[i] += boffs[i / SCAN_BLK];
    if (i == n) rp[n] = TOT;
}

// fill CSR (dst-grouped) with col + f32 weight, for the layer-1 gather
__global__ void k_fill(const int* __restrict__ src, const int* __restrict__ dst,
                       const int* __restrict__ rp, int* __restrict__ cursor,
                       int* __restrict__ col, float* __restrict__ wgt,
                       const float* __restrict__ dinv, int E) {
    int i = blockIdx.x * blockDim.x + threadIdx.x;
    if (i < E) {
        int d = dst[i], s = src[i];
        int p = atomicAdd(&cursor[d], 1);
        int idx = rp[d] + p;
        col[idx] = s;
        wgt[idx] = dinv[d] * dinv[s];
    }
}

// CSC-like src-grouped pool records: slot rps[v] = self record {v, g(batch), dv^2}
__global__ void k_selfrec(const int* __restrict__ rps, const int* __restrict__ batch,
                          const float* __restrict__ dinv, int2* __restrict__ recs, int n) {
    int v = blockIdx.x * blockDim.x + threadIdx.x;
    if (v < n) {
        float dv = dinv[v];
        int2 r; r.x = v; r.y = packgw(dv * dv, batch[v]);
        recs[rps[v]] = r;
    }
}

__global__ void k_fill2(const int* __restrict__ src, const int* __restrict__ dst,
                        const int* __restrict__ rps, int* __restrict__ cursor2,
                        const int* __restrict__ batch, const float* __restrict__ dinv,
                        int2* __restrict__ recs, int E) {
    int i = blockIdx.x * blockDim.x + threadIdx.x;
    if (i < E) {
        int s = src[i], d = dst[i];
        int p = atomicAdd(&cursor2[s], 1);
        int2 r; r.x = s; r.y = packgw(dinv[s] * dinv[d], batch[d]);
        recs[rps[s] + 1 + p] = r;
    }
}

__global__ void k_cnt(const int* __restrict__ batch, int* __restrict__ cnt, int n) {
    int i = blockIdx.x * blockDim.x + threadIdx.x;
    if (i < n) atomicAdd(&cnt[batch[i]], 1);
}

// ---------------------------------------------------------------------------
// layer-1 gather (round-3 proven form): wave = 4 groups x 16 lanes; each lane
// loads 16B, a group covers one 256B row, 2-deep software pipeline.
__global__ __launch_bounds__(256) void k_agg1(
    const unsigned* __restrict__ X2, unsigned* __restrict__ O2,
    const int* __restrict__ rp, const int* __restrict__ col,
    const float* __restrict__ wgt, const float* __restrict__ dinv)
{
    int lane = threadIdx.x & 63;
    int grp  = lane >> 4;
    int fl   = lane & 15;
    int v = (blockIdx.x << 2) + (threadIdx.x >> 6);
    if (v >= N_NODES) return;
    float dv = dinv[v];
    int e0 = rp[v];
    int L  = rp[v + 1] - e0 + 1;    // self + edges
    float acc[8] = {0.f,0.f,0.f,0.f,0.f,0.f,0.f,0.f};
    int i = grp;
    int sA = -1, sB = -1; float wA = 0.f, wB = 0.f;
    if (i < L) {
        if (i == 0) { sA = v; wA = dv * dv; }
        else        { sA = col[e0 + i - 1]; wA = wgt[e0 + i - 1]; }
    }
    if (i + 4 < L) { sB = col[e0 + i + 3]; wB = wgt[e0 + i + 3]; }
    while (sA >= 0) {
        int sC = -1, sD = -1; float wC = 0.f, wD = 0.f;
        if (i + 8  < L) { sC = col[e0 + i + 7];  wC = wgt[e0 + i + 7]; }
        if (i + 12 < L) { sD = col[e0 + i + 11]; wD = wgt[e0 + i + 11]; }
        uint4 uA = *(const uint4*)(X2 + (size_t)sA * 64 + fl * 4);
        uint4 uB;
        bool hB = (sB >= 0);
        if (hB) uB = *(const uint4*)(X2 + (size_t)sB * 64 + fl * 4);
        fma8(acc, wA, uA);
        if (hB) fma8(acc, wB, uB);
        i += 8; sA = sC; wA = wC; sB = sD; wB = wD;
    }
#pragma unroll
    for (int j = 0; j < 8; ++j) {
        acc[j] += __shfl_xor(acc[j], 16, 64);
        acc[j] += __shfl_xor(acc[j], 32, 64);
    }
    if (grp == 0) {
        uint4 o;
        o.x = packbf2(acc[0], acc[1]);
        o.y = packbf2(acc[2], acc[3]);
        o.z = packbf2(acc[4], acc[5]);
        o.w = packbf2(acc[6], acc[7]);
        *(uint4*)(O2 + (size_t)v * 64 + fl * 4) = o;
    }
}

// ---------------------------------------------------------------------------
// B = relu(A @ W1 + b1), dense bf16 rows, MFMA
__global__ __launch_bounds__(256) void k_gemm_mfma(
    const unsigned short* __restrict__ A, const unsigned short* __restrict__ Wt,
    const float* __restrict__ bias, unsigned short* __restrict__ B)
{
    int lane = threadIdx.x & 63;
    int wv = threadIdx.x >> 6;
    size_t row0 = (size_t)blockIdx.x * 64 + (size_t)wv * 16;
    int r = lane & 15, g = lane >> 4;

    short8v af[4];
    const unsigned short* arow = A + (row0 + r) * FDIM + g * 8;
#pragma unroll
    for (int ks = 0; ks < 4; ++ks)
        af[ks] = *(const short8v*)(arow + ks * 32);

    f32x4 acc[8];
#pragma unroll
    for (int ct = 0; ct < 8; ++ct) {
        f32x4 a = {0.f, 0.f, 0.f, 0.f};
        const unsigned short* wrow = Wt + (ct * 16 + r) * FDIM + g * 8;
#pragma unroll
        for (int ks = 0; ks < 4; ++ks) {
            short8v bfr = *(const short8v*)(wrow + ks * 32);
            a = __builtin_amdgcn_mfma_f32_16x16x32_bf16(af[ks], bfr, a, 0, 0, 0);
        }
        acc[ct] = a;
    }

#pragma unroll
    for (int ct = 0; ct < 8; ++ct) {
        int c = ct * 16 + r;
        float bs = bias[c];
#pragma unroll
        for (int i = 0; i < 4; ++i) {
            size_t row = row0 + g * 4 + i;
            if (row < N_NODES) {
                float vv = fmaxf(acc[ct][i] + bs, 0.f);
                B[row * FDIM + c] = f2bf(vv);
            }
        }
    }
}

// ---------------------------------------------------------------------------
// pooled layer-2: P[g] += w * H[src] for src-sorted records; per-graph
// accumulator (1024 x 32 feats quarter) lives in LDS. block = chunk x quarter.
__global__ __launch_bounds__(512) void k_pool(
    const unsigned* __restrict__ H2, const int2* __restrict__ recs,
    const int* __restrict__ rps, float* __restrict__ Ppart)
{
    __shared__ float pl[N_GRAPHS][32];
    int c = blockIdx.x >> 2;        // src chunk
    int q = blockIdx.x & 3;         // feature quarter
    int t = threadIdx.x;
    for (int i = t; i < N_GRAPHS * 32; i += 512) ((float*)pl)[i] = 0.f;
    __syncthreads();

    int v0 = c * CHUNK, v1 = min(v0 + CHUNK, N_NODES);
    int e0 = rps[v0], e1 = rps[v1];
    int f  = t & 31;                // feature within quarter
    int uo = q * 16 + (f >> 1);     // uint offset in row
    bool hi = (f & 1);

    int e = e0 + (t >> 5);          // 16 half-waves stride the records
    if (e < e1) {
        int2 r = recs[e];
        unsigned u = H2[(size_t)r.x * 64 + uo];
        for (;;) {
            int en = e + 16;
            bool more = (en < e1);
            int2 rn; unsigned un;
            if (more) {
                rn = recs[en];
                un = H2[(size_t)rn.x * 64 + uo];
            }
            int g = r.y & 1023;
            float w = __int_as_float(r.y & ~1023);
            atomicAdd(&pl[g][f], w * (hi ? bfhi(u) : bflo(u)));
            if (!more) break;
            e = en; r = rn; u = un;
        }
    }
    __syncthreads();
    float* dst = Ppart + ((size_t)(q * NCHUNK + c)) * (N_GRAPHS * 32);
    for (int i = t; i < N_GRAPHS * 32; i += 512) dst[i] = ((float*)pl)[i];
}

// reduce chunk partials into P[g][128]
__global__ void k_pred(const float* __restrict__ Ppart, float* __restrict__ P) {
    int i = blockIdx.x * blockDim.x + threadIdx.x;   // g*128 + f
    if (i >= N_GRAPHS * FDIM) return;
    int f = i & 127, g = i >> 7;
    int q = f >> 5, j = f & 31;
    float acc = 0.f;
    const float* base = Ppart + ((size_t)q * NCHUNK) * (N_GRAPHS * 32) + (size_t)g * 32 + j;
#pragma unroll 4
    for (int c = 0; c < NCHUNK; ++c)
        acc += base[(size_t)c * (N_GRAPHS * 32)];
    P[i] = acc;
}

// ---------------------------------------------------------------------------
__global__ void k_wcomb(const float* __restrict__ W2, const float* __restrict__ Wf,
                        const float* __restrict__ b2, const float* __restrict__ bf,
                        float* __restrict__ Wc, float* __restrict__ bc) {
    int idx = blockIdx.x * blockDim.x + threadIdx.x;
    if (idx < 128 * 32) {
        int k = idx >> 5, c = idx & 31;
        float acc = 0.0f;
        for (int m = 0; m < 128; ++m) acc += W2[k * 128 + m] * Wf[m * 32 + c];
        Wc[idx] = acc;
    }
    if (idx < 32) {
        float acc = bf[idx];
        for (int m = 0; m < 128; ++m) acc += b2[m] * Wf[m * 32 + idx];
        bc[idx] = acc;
    }
}

__global__ void k_final(const float* __restrict__ P, const int* __restrict__ cnt,
                        const float* __restrict__ Wc, const float* __restrict__ bc,
                        const float* __restrict__ bf, float* __restrict__ out) {
    __shared__ float p[128];
    int g = blockIdx.x, t = threadIdx.x;
    int c_ = cnt[g];
    float inv = (c_ > 0) ? 1.0f / (float)c_ : 0.0f;
    p[t] = P[(size_t)g * FDIM + t] * inv;
    __syncthreads();
    if (t < N_CLASSES) {
        float acc = (c_ > 0) ? bc[t] : bf[t];
#pragma unroll
        for (int k = 0; k < 128; ++k) acc = fmaf(p[k], Wc[k * 32 + t], acc);
        out[(size_t)g * N_CLASSES + t] = acc;
    }
}

// ---------------------------------------------------------------------------
extern "C" void kernel_launch(void* const* d_in, const int* in_sizes, int n_in,
                              void* d_out, int out_size, void* d_ws, size_t ws_size,
                              hipStream_t stream) {
    const float* x    = (const float*)d_in[0];
    const int*   ei   = (const int*)d_in[1];
    const int*   batch= (const int*)d_in[2];
    const float* W1   = (const float*)d_in[3];
    const float* b1   = (const float*)d_in[4];
    const float* W2   = (const float*)d_in[5];
    const float* b2   = (const float*)d_in[6];
    const float* Wf   = (const float*)d_in[7];
    const float* bf   = (const float*)d_in[8];
    const int* src = ei;
    const int* dst = ei + N_EDGES;

    char* w = (char*)d_ws;
    auto alloc = [&](size_t bytes) { char* p = w; w += (bytes + 255) & ~255ull; return p; };
    int*      indeg  = (int*)     alloc((size_t)N_NODES * 4);
    int*      odeg   = (int*)     alloc((size_t)N_NODES * 4);
    float*    dinv   = (float*)   alloc((size_t)N_NODES * 4);
    int*      rp     = (int*)     alloc((size_t)(N_NODES + 1) * 4);
    int*      rps    = (int*)     alloc((size_t)(N_NODES + 1) * 4);
    int*      cursor = (int*)     alloc((size_t)N_NODES * 4);
    int*      cursor2= (int*)     alloc((size_t)N_NODES * 4);
    int*      bsums  = (int*)     alloc(1024 * 4);
    int*      col    = (int*)     alloc((size_t)N_EDGES * 4);
    float*    wgt    = (float*)   alloc((size_t)N_EDGES * 4);
    int2*     recs   = (int2*)    alloc((size_t)(N_EDGES + N_NODES) * 8);
    unsigned* xh     = (unsigned*)alloc((size_t)N_NODES * 64 * 4);
    unsigned* Ab     = (unsigned*)alloc((size_t)M_PAD  * 64 * 4);
    unsigned* Bb     = (unsigned*)alloc((size_t)N_NODES * 64 * 4);
    unsigned short* Wt = (unsigned short*)alloc(128 * 128 * 2);
    float*    Ppart  = (float*)   alloc((size_t)4 * NCHUNK * N_GRAPHS * 32 * 4);
    float*    P      = (float*)   alloc((size_t)N_GRAPHS * FDIM * 4);
    int*      cnt    = (int*)     alloc((size_t)N_GRAPHS * 4);
    float*    Wc     = (float*)   alloc(128 * 32 * 4);
    float*    bc     = (float*)   alloc(32 * 4);

    hipMemsetAsync(indeg,   0, (size_t)N_NODES * 4, stream);
    hipMemsetAsync(odeg,    0, (size_t)N_NODES * 4, stream);
    hipMemsetAsync(cursor,  0, (size_t)N_NODES * 4, stream);
    hipMemsetAsync(cursor2, 0, (size_t)N_NODES * 4, stream);
    hipMemsetAsync(cnt,     0, (size_t)N_GRAPHS * 4, stream);

    const int nbScan = (N_NODES + SCAN_BLK - 1) / SCAN_BLK;   // 98

    // input conversions (independent of CSR build)
    k_f2bf<<<(N_NODES * 64 + 255) / 256, 256, 0, stream>>>(x, xh, N_NODES * 64);
    k_wt  <<<64, 256, 0, stream>>>(W1, Wt);

    // degree counts
    k_count<<<(N_EDGES + 255) / 256, 256, 0, stream>>>(dst, indeg, N_EDGES);
    k_count<<<(N_EDGES + 255) / 256, 256, 0, stream>>>(src, odeg, N_EDGES);
    k_dinv <<<(N_NODES + 255) / 256, 256, 0, stream>>>(indeg, dinv, N_NODES);
    k_p1   <<<(N_NODES + 255) / 256, 256, 0, stream>>>(odeg, N_NODES);   // self slot

    // CSR scan (dst-grouped, for layer-1 gather)
    k_scan1<<<nbScan, 256, 0, stream>>>(indeg, rp, bsums, N_NODES);
    k_scan2<<<1, 256, 0, stream>>>(bsums, nbScan);
    k_scan3<<<(N_NODES + 1 + 255) / 256, 256, 0, stream>>>(rp, bsums, N_NODES, N_EDGES);
    // CSC scan (src-grouped incl. self slots, for pool)
    k_scan1<<<nbScan, 256, 0, stream>>>(odeg, rps, bsums, N_NODES);
    k_scan2<<<1, 256, 0, stream>>>(bsums, nbScan);
    k_scan3<<<(N_NODES + 1 + 255) / 256, 256, 0, stream>>>(rps, bsums, N_NODES, N_EDGES + N_NODES);

    // fills
    k_fill   <<<(N_EDGES + 255) / 256, 256, 0, stream>>>(src, dst, rp, cursor, col, wgt, dinv, N_EDGES);
    k_selfrec<<<(N_NODES + 255) / 256, 256, 0, stream>>>(rps, batch, dinv, recs, N_NODES);
    k_fill2  <<<(N_EDGES + 255) / 256, 256, 0, stream>>>(src, dst, rps, cursor2, batch, dinv, recs, N_EDGES);
    k_cnt    <<<(N_NODES + 255) / 256, 256, 0, stream>>>(batch, cnt, N_NODES);

    // layer 1: gather then MFMA GEMM + bias + relu
    k_agg1<<<(N_NODES + 3) / 4, 256, 0, stream>>>(xh, Ab, rp, col, wgt, dinv);
    k_gemm_mfma<<<M_PAD / 64, 256, 0, stream>>>((const unsigned short*)Ab, Wt, b1,
                                                (unsigned short*)Bb);

    // classifier weight folding (tiny, independent)
    k_wcomb<<<16, 256, 0, stream>>>(W2, Wf, b2, bf, Wc, bc);

    // layer 2 + mean-pool: streaming scatter into LDS per-graph accumulators
    k_pool<<<NCHUNK * 4, 512, 0, stream>>>(Bb, recs, rps, Ppart);
    k_pred<<<(N_GRAPHS * FDIM + 255) / 256, 256, 0, stream>>>(Ppart, P);

    // final: mean, fold through Wc=W2@Wf, write [1024,32]
    k_final<<<N_GRAPHS, 128, 0, stream>>>(P, cnt, Wc, bc, bf, (float*)d_out);
}

// Round 6
// 1558.505 us; speedup vs baseline: 1.1049x; 1.1049x over previous
//
#include <hip/hip_runtime.h>
#include <hip/hip_bf16.h>

#define N_NODES   100000
#define N_EDGES   1600000
#define FDIM      128
#define N_GRAPHS  1024
#define N_CLASSES 32
#define SCAN_BLK  1024
#define M_PAD     100032            // padded rows for 64-row GEMM tiles
#define PCHUNK    1563              // sources per pool chunk (64*1563 >= N)
#define NPCH      64

typedef __attribute__((ext_vector_type(8))) short short8v;
typedef __attribute__((ext_vector_type(4))) float f32x4;

__device__ __forceinline__ float bflo(unsigned u){ union{unsigned i; float f;} c; c.i = u << 16; return c.f; }
__device__ __forceinline__ float bfhi(unsigned u){ union{unsigned i; float f;} c; c.i = u & 0xffff0000u; return c.f; }
__device__ __forceinline__ unsigned short f2bf(float f){
    union{float f; unsigned u;} c{f};
    return (unsigned short)((c.u + 0x7fffu + ((c.u >> 16) & 1u)) >> 16);
}
__device__ __forceinline__ unsigned packbf2(float a, float b){
    return (unsigned)f2bf(a) | ((unsigned)f2bf(b) << 16);
}
// pack graph id into low 10 mantissa bits of w (w in (0,1], normal): rel err <= 2^-12
__device__ __forceinline__ int packgw(float w, int g){
    return (__float_as_int(w) & ~1023) | g;
}

__device__ __forceinline__ void fma8(float* acc, float w, uint4 u) {
    acc[0] += w * bflo(u.x); acc[1] += w * bfhi(u.x);
    acc[2] += w * bflo(u.y); acc[3] += w * bfhi(u.y);
    acc[4] += w * bflo(u.z); acc[5] += w * bfhi(u.z);
    acc[6] += w * bflo(u.w); acc[7] += w * bfhi(u.w);
}

// ---------------------------------------------------------------------------
__global__ void k_f2bf(const float* __restrict__ in, unsigned* __restrict__ out, int n2) {
    int i = blockIdx.x * blockDim.x + threadIdx.x;
    if (i < n2) {
        float2 v = ((const float2*)in)[i];
        out[i] = packbf2(v.x, v.y);
    }
}

__global__ void k_wt(const float* __restrict__ W, unsigned short* __restrict__ Wt) {
    int i = blockIdx.x * blockDim.x + threadIdx.x;   // 16384
    int k = i >> 7, n = i & 127;
    Wt[n * 128 + k] = f2bf(W[i]);
}

// ---------------------------------------------------------------------------
// both degree counts in one pass over the edge list
__global__ void k_count2(const int* __restrict__ src, const int* __restrict__ dst,
                         int* __restrict__ indeg, int* __restrict__ odeg, int E) {
    int i = blockIdx.x * blockDim.x + threadIdx.x;
    if (i < E) {
        atomicAdd(&indeg[dst[i]], 1);
        atomicAdd(&odeg[src[i]], 1);
    }
}

// dinv from indeg; odeg += 1 (self slot for the pool record list)
__global__ void k_dinvp1(const int* __restrict__ indeg, float* __restrict__ dinv,
                         int* __restrict__ odeg, int n) {
    int i = blockIdx.x * blockDim.x + threadIdx.x;
    if (i < n) {
        dinv[i] = rsqrtf((float)(indeg[i] + 1));
        odeg[i] += 1;
    }
}

// dual prefix scans (blockIdx.y: 0 = indeg->rp, 1 = odeg->rps)
__global__ void k_scan1(const int* __restrict__ in0, const int* __restrict__ in1,
                        int* __restrict__ out0, int* __restrict__ out1,
                        int* __restrict__ bsums, int n) {
    __shared__ int lds[256];
    const int* in = blockIdx.y ? in1 : in0;
    int* out      = blockIdx.y ? out1 : out0;
    int* bs       = bsums + blockIdx.y * 1024;
    int blk = blockIdx.x, t = threadIdx.x;
    int base = blk * SCAN_BLK + t * 4;
    int v[4];
#pragma unroll
    for (int i = 0; i < 4; ++i) v[i] = (base + i < n) ? in[base + i] : 0;
    int local = v[0] + v[1] + v[2] + v[3];
    lds[t] = local;
    __syncthreads();
    for (int off = 1; off < 256; off <<= 1) {
        int x = lds[t];
        int y = (t >= off) ? lds[t - off] : 0;
        __syncthreads();
        lds[t] = x + y;
        __syncthreads();
    }
    int excl = lds[t] - local;
    if (t == 255) bs[blk] = lds[255];
    int run = excl;
#pragma unroll
    for (int i = 0; i < 4; ++i) {
        if (base + i < n) { out[base + i] = run; run += v[i]; }
    }
}

__global__ void k_scan2(int* __restrict__ bsums, int nb) {
    __shared__ int lds[256];
    int* bs = bsums + blockIdx.y * 1024;
    int t = threadIdx.x;
    int orig = (t < nb) ? bs[t] : 0;
    lds[t] = orig;
    __syncthreads();
    for (int off = 1; off < 256; off <<= 1) {
        int x = lds[t];
        int y = (t >= off) ? lds[t - off] : 0;
        __syncthreads();
        lds[t] = x + y;
        __syncthreads();
    }
    if (t < nb) bs[t] = lds[t] - orig;
}

__global__ void k_scan3(int* __restrict__ rp, int* __restrict__ rps,
                        const int* __restrict__ bsums, int n) {
    int* arr       = blockIdx.y ? rps : rp;
    const int* bo  = bsums + blockIdx.y * 1024;
    int TOT        = blockIdx.y ? (N_EDGES + N_NODES) : N_EDGES;
    int i = blockIdx.x * blockDim.x + threadIdx.x;
    if (i < n) arr[i] += bo[i / SCAN_BLK];
    if (i == n) arr[n] = TOT;
}

// one pass over edges: CSR(dst) fill for the gather + src-grouped pool records
__global__ void k_fillboth(const int* __restrict__ src, const int* __restrict__ dst,
                           const int* __restrict__ rp, int* __restrict__ cursor,
                           int* __restrict__ col, float* __restrict__ wgt,
                           const int* __restrict__ rps, int* __restrict__ cursor2,
                           const int* __restrict__ batch, int2* __restrict__ recs,
                           const float* __restrict__ dinv, int E) {
    int i = blockIdx.x * blockDim.x + threadIdx.x;
    if (i < E) {
        int d = dst[i], s = src[i];
        float w = dinv[d] * dinv[s];
        int p = atomicAdd(&cursor[d], 1);
        int idx = rp[d] + p;
        col[idx] = s;
        wgt[idx] = w;
        int p2 = atomicAdd(&cursor2[s], 1);
        int2 r; r.x = s; r.y = packgw(w, batch[d]);
        recs[rps[s] + 1 + p2] = r;
    }
}

// self records + per-graph node counts
__global__ void k_selfcnt(const int* __restrict__ rps, const int* __restrict__ batch,
                          const float* __restrict__ dinv, int2* __restrict__ recs,
                          int* __restrict__ cnt, int n) {
    int v = blockIdx.x * blockDim.x + threadIdx.x;
    if (v < n) {
        float dv = dinv[v];
        int g = batch[v];
        int2 r; r.x = v; r.y = packgw(dv * dv, g);
        recs[rps[v]] = r;
        atomicAdd(&cnt[g], 1);
    }
}

// ---------------------------------------------------------------------------
// layer-1 gather (round-3 proven form): wave = 4 groups x 16 lanes; each lane
// loads 16B, a group covers one 256B row, 2-deep software pipeline.
__global__ __launch_bounds__(256) void k_agg1(
    const unsigned* __restrict__ X2, unsigned* __restrict__ O2,
    const int* __restrict__ rp, const int* __restrict__ col,
    const float* __restrict__ wgt, const float* __restrict__ dinv)
{
    int lane = threadIdx.x & 63;
    int grp  = lane >> 4;
    int fl   = lane & 15;
    int v = (blockIdx.x << 2) + (threadIdx.x >> 6);
    if (v >= N_NODES) return;
    float dv = dinv[v];
    int e0 = rp[v];
    int L  = rp[v + 1] - e0 + 1;    // self + edges
    float acc[8] = {0.f,0.f,0.f,0.f,0.f,0.f,0.f,0.f};
    int i = grp;
    int sA = -1, sB = -1; float wA = 0.f, wB = 0.f;
    if (i < L) {
        if (i == 0) { sA = v; wA = dv * dv; }
        else        { sA = col[e0 + i - 1]; wA = wgt[e0 + i - 1]; }
    }
    if (i + 4 < L) { sB = col[e0 + i + 3]; wB = wgt[e0 + i + 3]; }
    while (sA >= 0) {
        int sC = -1, sD = -1; float wC = 0.f, wD = 0.f;
        if (i + 8  < L) { sC = col[e0 + i + 7];  wC = wgt[e0 + i + 7]; }
        if (i + 12 < L) { sD = col[e0 + i + 11]; wD = wgt[e0 + i + 11]; }
        uint4 uA = *(const uint4*)(X2 + (size_t)sA * 64 + fl * 4);
        uint4 uB;
        bool hB = (sB >= 0);
        if (hB) uB = *(const uint4*)(X2 + (size_t)sB * 64 + fl * 4);
        fma8(acc, wA, uA);
        if (hB) fma8(acc, wB, uB);
        i += 8; sA = sC; wA = wC; sB = sD; wB = wD;
    }
#pragma unroll
    for (int j = 0; j < 8; ++j) {
        acc[j] += __shfl_xor(acc[j], 16, 64);
        acc[j] += __shfl_xor(acc[j], 32, 64);
    }
    if (grp == 0) {
        uint4 o;
        o.x = packbf2(acc[0], acc[1]);
        o.y = packbf2(acc[2], acc[3]);
        o.z = packbf2(acc[4], acc[5]);
        o.w = packbf2(acc[6], acc[7]);
        *(uint4*)(O2 + (size_t)v * 64 + fl * 4) = o;
    }
}

// ---------------------------------------------------------------------------
// B = relu(A @ W1 + b1), dense bf16 rows, MFMA
__global__ __launch_bounds__(256) void k_gemm_mfma(
    const unsigned short* __restrict__ A, const unsigned short* __restrict__ Wt,
    const float* __restrict__ bias, unsigned short* __restrict__ B)
{
    int lane = threadIdx.x & 63;
    int wv = threadIdx.x >> 6;
    size_t row0 = (size_t)blockIdx.x * 64 + (size_t)wv * 16;
    int r = lane & 15, g = lane >> 4;

    short8v af[4];
    const unsigned short* arow = A + (row0 + r) * FDIM + g * 8;
#pragma unroll
    for (int ks = 0; ks < 4; ++ks)
        af[ks] = *(const short8v*)(arow + ks * 32);

    f32x4 acc[8];
#pragma unroll
    for (int ct = 0; ct < 8; ++ct) {
        f32x4 a = {0.f, 0.f, 0.f, 0.f};
        const unsigned short* wrow = Wt + (ct * 16 + r) * FDIM + g * 8;
#pragma unroll
        for (int ks = 0; ks < 4; ++ks) {
            short8v bfr = *(const short8v*)(wrow + ks * 32);
            a = __builtin_amdgcn_mfma_f32_16x16x32_bf16(af[ks], bfr, a, 0, 0, 0);
        }
        acc[ct] = a;
    }

#pragma unroll
    for (int ct = 0; ct < 8; ++ct) {
        int c = ct * 16 + r;
        float bs = bias[c];
#pragma unroll
        for (int i = 0; i < 4; ++i) {
            size_t row = row0 + g * 4 + i;
            if (row < N_NODES) {
                float vv = fmaxf(acc[ct][i] + bs, 0.f);
                B[row * FDIM + c] = f2bf(vv);
            }
        }
    }
}

// ---------------------------------------------------------------------------
// layer-2 + pool: P[g] += w * H[src] over src-sorted records.
// block = (chunk, feature-octant): LDS accumulator 1024 x 16 = 64KB -> 2 blocks/CU.
// 128 record-streams per block (4 lanes/record, uint2 = 4 feats per lane).
__global__ __launch_bounds__(512) void k_pool(
    const unsigned* __restrict__ H2, const int2* __restrict__ recs,
    const int* __restrict__ rps, float* __restrict__ Ppart)
{
    __shared__ float pl[N_GRAPHS][16];
    int c   = blockIdx.x >> 3;      // src chunk
    int oct = blockIdx.x & 7;       // feature octant (16 feats)
    int t = threadIdx.x;
    for (int i = t; i < N_GRAPHS * 16; i += 512) ((float*)pl)[i] = 0.f;
    __syncthreads();

    int v0 = c * PCHUNK, v1 = min(v0 + PCHUNK, N_NODES);
    int e0 = rps[v0], e1 = rps[v1];
    int sl = t & 3;                 // sub-lane within 4-lane record group
    int uo = oct * 8 + sl * 2;      // uint2 offset in the 64-uint row
    int fb = sl * 4;                // feature base within octant

    int e = e0 + (t >> 2);          // 128 streams stride the record window
    if (e < e1) {
        int2 r = recs[e];
        uint2 u = *(const uint2*)(H2 + (size_t)r.x * 64 + uo);
        for (;;) {
            int en = e + 128;
            bool more = (en < e1);
            int2 rn; uint2 un;
            if (more) {
                rn = recs[en];
                un = *(const uint2*)(H2 + (size_t)rn.x * 64 + uo);
            }
            int g = r.y & 1023;
            float w = __int_as_float(r.y & ~1023);
            atomicAdd(&pl[g][fb + 0], w * bflo(u.x));
            atomicAdd(&pl[g][fb + 1], w * bfhi(u.x));
            atomicAdd(&pl[g][fb + 2], w * bflo(u.y));
            atomicAdd(&pl[g][fb + 3], w * bfhi(u.y));
            if (!more) break;
            e = en; r = rn; u = un;
        }
    }
    __syncthreads();
    float* dst = Ppart + (size_t)blockIdx.x * (N_GRAPHS * 16);
    for (int i = t; i < N_GRAPHS * 16; i += 512) dst[i] = ((float*)pl)[i];
}

// reduce chunk partials into P[g][128]; Ppart[(c*8+oct)][g][16]
__global__ void k_pred(const float* __restrict__ Ppart, float* __restrict__ P) {
    int i = blockIdx.x * blockDim.x + threadIdx.x;   // g*128 + f
    if (i >= N_GRAPHS * FDIM) return;
    int f = i & 127, g = i >> 7;
    int oct = f >> 4, j = f & 15;
    float acc = 0.f;
    const float* base = Ppart + (size_t)oct * (N_GRAPHS * 16) + (size_t)g * 16 + j;
#pragma unroll 4
    for (int c = 0; c < NPCH; ++c)
        acc += base[(size_t)c * 8 * (N_GRAPHS * 16)];
    P[i] = acc;
}

// ---------------------------------------------------------------------------
__global__ void k_wcomb(const float* __restrict__ W2, const float* __restrict__ Wf,
                        const float* __restrict__ b2, const float* __restrict__ bf,
                        float* __restrict__ Wc, float* __restrict__ bc) {
    int idx = blockIdx.x * blockDim.x + threadIdx.x;
    if (idx < 128 * 32) {
        int k = idx >> 5, c = idx & 31;
        float acc = 0.0f;
        for (int m = 0; m < 128; ++m) acc += W2[k * 128 + m] * Wf[m * 32 + c];
        Wc[idx] = acc;
    }
    if (idx < 32) {
        float acc = bf[idx];
        for (int m = 0; m < 128; ++m) acc += b2[m] * Wf[m * 32 + idx];
        bc[idx] = acc;
    }
}

__global__ void k_final(const float* __restrict__ P, const int* __restrict__ cnt,
                        const float* __restrict__ Wc, const float* __restrict__ bc,
                        const float* __restrict__ bf, float* __restrict__ out) {
    __shared__ float p[128];
    int g = blockIdx.x, t = threadIdx.x;
    int c_ = cnt[g];
    float inv = (c_ > 0) ? 1.0f / (float)c_ : 0.0f;
    p[t] = P[(size_t)g * FDIM + t] * inv;
    __syncthreads();
    if (t < N_CLASSES) {
        float acc = (c_ > 0) ? bc[t] : bf[t];
#pragma unroll
        for (int k = 0; k < 128; ++k) acc = fmaf(p[k], Wc[k * 32 + t], acc);
        out[(size_t)g * N_CLASSES + t] = acc;
    }
}

// ---------------------------------------------------------------------------
extern "C" void kernel_launch(void* const* d_in, const int* in_sizes, int n_in,
                              void* d_out, int out_size, void* d_ws, size_t ws_size,
                              hipStream_t stream) {
    const float* x    = (const float*)d_in[0];
    const int*   ei   = (const int*)d_in[1];
    const int*   batch= (const int*)d_in[2];
    const float* W1   = (const float*)d_in[3];
    const float* b1   = (const float*)d_in[4];
    const float* W2   = (const float*)d_in[5];
    const float* b2   = (const float*)d_in[6];
    const float* Wf   = (const float*)d_in[7];
    const float* bf   = (const float*)d_in[8];
    const int* src = ei;
    const int* dst = ei + N_EDGES;

    char* w = (char*)d_ws;
    auto alloc = [&](size_t bytes) { char* p = w; w += (bytes + 255) & ~255ull; return p; };
    int*      indeg  = (int*)     alloc((size_t)N_NODES * 4);
    int*      odeg   = (int*)     alloc((size_t)N_NODES * 4);
    float*    dinv   = (float*)   alloc((size_t)N_NODES * 4);
    int*      rp     = (int*)     alloc((size_t)(N_NODES + 1) * 4);
    int*      rps    = (int*)     alloc((size_t)(N_NODES + 1) * 4);
    int*      cursor = (int*)     alloc((size_t)N_NODES * 4);
    int*      cursor2= (int*)     alloc((size_t)N_NODES * 4);
    int*      bsums  = (int*)     alloc(2 * 1024 * 4);
    int*      col    = (int*)     alloc((size_t)N_EDGES * 4);
    float*    wgt    = (float*)   alloc((size_t)N_EDGES * 4);
    int2*     recs   = (int2*)    alloc((size_t)(N_EDGES + N_NODES) * 8);
    unsigned* xh     = (unsigned*)alloc((size_t)N_NODES * 64 * 4);
    unsigned* Ab     = (unsigned*)alloc((size_t)M_PAD  * 64 * 4);
    unsigned* Bb     = (unsigned*)alloc((size_t)N_NODES * 64 * 4);
    unsigned short* Wt = (unsigned short*)alloc(128 * 128 * 2);
    float*    Ppart  = (float*)   alloc((size_t)NPCH * 8 * N_GRAPHS * 16 * 4);
    float*    P      = (float*)   alloc((size_t)N_GRAPHS * FDIM * 4);
    int*      cnt    = (int*)     alloc((size_t)N_GRAPHS * 4);
    float*    Wc     = (float*)   alloc(128 * 32 * 4);
    float*    bc     = (float*)   alloc(32 * 4);

    hipMemsetAsync(indeg,   0, (size_t)N_NODES * 4, stream);
    hipMemsetAsync(odeg,    0, (size_t)N_NODES * 4, stream);
    hipMemsetAsync(cursor,  0, (size_t)N_NODES * 4, stream);
    hipMemsetAsync(cursor2, 0, (size_t)N_NODES * 4, stream);
    hipMemsetAsync(cnt,     0, (size_t)N_GRAPHS * 4, stream);

    const int nbScan = (N_NODES + SCAN_BLK - 1) / SCAN_BLK;   // 98

    // input conversions (independent of CSR build)
    k_f2bf<<<(N_NODES * 64 + 255) / 256, 256, 0, stream>>>(x, xh, N_NODES * 64);
    k_wt  <<<64, 256, 0, stream>>>(W1, Wt);

    // degrees + dinv
    k_count2<<<(N_EDGES + 255) / 256, 256, 0, stream>>>(src, dst, indeg, odeg, N_EDGES);
    k_dinvp1<<<(N_NODES + 255) / 256, 256, 0, stream>>>(indeg, dinv, odeg, N_NODES);

    // dual scans: indeg->rp, odeg->rps
    k_scan1<<<dim3(nbScan, 2), 256, 0, stream>>>(indeg, odeg, rp, rps, bsums, N_NODES);
    k_scan2<<<dim3(1, 2), 256, 0, stream>>>(bsums, nbScan);
    k_scan3<<<dim3((N_NODES + 1 + 255) / 256, 2), 256, 0, stream>>>(rp, rps, bsums, N_NODES);

    // fills (CSR + pool records + cnt)
    k_fillboth<<<(N_EDGES + 255) / 256, 256, 0, stream>>>(src, dst, rp, cursor, col, wgt,
                                                          rps, cursor2, batch, recs, dinv, N_EDGES);
    k_selfcnt<<<(N_NODES + 255) / 256, 256, 0, stream>>>(rps, batch, dinv, recs, cnt, N_NODES);

    // layer 1: gather then MFMA GEMM + bias + relu
    k_agg1<<<N_NODES / 4, 256, 0, stream>>>(xh, Ab, rp, col, wgt, dinv);
    k_gemm_mfma<<<M_PAD / 64, 256, 0, stream>>>((const unsigned short*)Ab, Wt, b1,
                                                (unsigned short*)Bb);

    // classifier weight folding (tiny, independent)
    k_wcomb<<<16, 256, 0, stream>>>(W2, Wf, b2, bf, Wc, bc);

    // layer 2 + mean-pool: streaming src-sorted records into LDS per-graph accums
    k_pool<<<NPCH * 8, 512, 0, stream>>>(Bb, recs, rps, Ppart);
    k_pred<<<(N_GRAPHS * FDIM + 255) / 256, 256, 0, stream>>>(Ppart, P);

    // final: mean, fold through Wc=W2@Wf, write [1024,32]
    k_final<<<N_GRAPHS, 128, 0, stream>>>(P, cnt, Wc, bc, bf, (float*)d_out);
}

// Round 8
// 993.212 us; speedup vs baseline: 1.7337x; 1.5692x over previous
//
#include <hip/hip_runtime.h>
#include <hip/hip_bf16.h>

#define N_NODES   100000
#define N_EDGES   1600000
#define FDIM      128
#define N_GRAPHS  1024
#define N_CLASSES 32
#define SCAN_BLK  1024
#define M_PAD     100032            // padded rows for 64-row GEMM tiles
#define SLICE_U   (M_PAD * 8)       // uints per 16-feature slice (32B rows)

typedef __attribute__((ext_vector_type(8))) short short8v;
typedef __attribute__((ext_vector_type(4))) float f32x4;
typedef __attribute__((ext_vector_type(4))) unsigned uint4v;
typedef __attribute__((ext_vector_type(2))) int int2v;

__device__ __forceinline__ float bflo(unsigned u){ union{unsigned i; float f;} c; c.i = u << 16; return c.f; }
__device__ __forceinline__ float bfhi(unsigned u){ union{unsigned i; float f;} c; c.i = u & 0xffff0000u; return c.f; }
__device__ __forceinline__ unsigned short f2bf(float f){
    union{float f; unsigned u;} c{f};
    return (unsigned short)((c.u + 0x7fffu + ((c.u >> 16) & 1u)) >> 16);
}
__device__ __forceinline__ unsigned packbf2(float a, float b){
    return (unsigned)f2bf(a) | ((unsigned)f2bf(b) << 16);
}

__device__ __forceinline__ void fma8(float* acc, float w, uint4v u) {
    acc[0] += w * bflo(u.x); acc[1] += w * bfhi(u.x);
    acc[2] += w * bflo(u.y); acc[3] += w * bfhi(u.y);
    acc[4] += w * bflo(u.z); acc[5] += w * bfhi(u.z);
    acc[6] += w * bflo(u.w); acc[7] += w * bfhi(u.w);
}

// ---------------------------------------------------------------------------
// fp32 x[v][128] -> bf16x2 XCD-sliced: xh[f*SLICE_U + v*8 + off], f = feat/16
__global__ void k_f2bf(const float* __restrict__ in, unsigned* __restrict__ out, int n2) {
    int i = blockIdx.x * blockDim.x + threadIdx.x;
    if (i < n2) {
        float2 v2 = ((const float2*)in)[i];
        int v = i >> 6, jp = i & 63;
        int f = jp >> 3, off = jp & 7;
        __builtin_nontemporal_store(packbf2(v2.x, v2.y),
                                    out + (size_t)f * SLICE_U + (size_t)v * 8 + off);
    }
}

__global__ void k_wt(const float* __restrict__ W, unsigned short* __restrict__ Wt) {
    int i = blockIdx.x * blockDim.x + threadIdx.x;   // 16384
    int k = i >> 7, n = i & 127;
    Wt[n * 128 + k] = f2bf(W[i]);
}

// ---------------------------------------------------------------------------
__global__ void k_count(const int* __restrict__ dst, int* __restrict__ indeg, int E) {
    int i = blockIdx.x * blockDim.x + threadIdx.x;
    if (i < E) atomicAdd(&indeg[dst[i]], 1);
}

// dinv + per-graph count + contiguous node range [r0,r1) (batch is sorted)
__global__ void k_prep(const int* __restrict__ indeg, float* __restrict__ dinv,
                       const int* __restrict__ batch, int* __restrict__ cnt,
                       int* __restrict__ r0, int* __restrict__ r1, int n) {
    int v = blockIdx.x * blockDim.x + threadIdx.x;
    if (v < n) {
        dinv[v] = rsqrtf((float)(indeg[v] + 1));
        int g = batch[v];
        atomicAdd(&cnt[g], 1);
        atomicMin(&r0[g], v);
        atomicMax(&r1[g], v + 1);
    }
}

__global__ void k_scan1(const int* __restrict__ in, int* __restrict__ out,
                        int* __restrict__ bsums, int n) {
    __shared__ int lds[256];
    int blk = blockIdx.x, t = threadIdx.x;
    int base = blk * SCAN_BLK + t * 4;
    int v[4];
#pragma unroll
    for (int i = 0; i < 4; ++i) v[i] = (base + i < n) ? in[base + i] : 0;
    int local = v[0] + v[1] + v[2] + v[3];
    lds[t] = local;
    __syncthreads();
    for (int off = 1; off < 256; off <<= 1) {
        int x = lds[t];
        int y = (t >= off) ? lds[t - off] : 0;
        __syncthreads();
        lds[t] = x + y;
        __syncthreads();
    }
    int excl = lds[t] - local;
    if (t == 255) bsums[blk] = lds[255];
    int run = excl;
#pragma unroll
    for (int i = 0; i < 4; ++i) {
        if (base + i < n) { out[base + i] = run; run += v[i]; }
    }
}

__global__ void k_scan2(int* __restrict__ bsums, int nb) {
    __shared__ int lds[256];
    int t = threadIdx.x;
    int orig = (t < nb) ? bsums[t] : 0;
    lds[t] = orig;
    __syncthreads();
    for (int off = 1; off < 256; off <<= 1) {
        int x = lds[t];
        int y = (t >= off) ? lds[t - off] : 0;
        __syncthreads();
        lds[t] = x + y;
        __syncthreads();
    }
    if (t < nb) bsums[t] = lds[t] - orig;
}

__global__ void k_scan3(int* __restrict__ rp, const int* __restrict__ boffs, int n, int E) {
    int i = blockIdx.x * blockDim.x + threadIdx.x;
    if (i < n) rp[i] += boffs[i / SCAN_BLK];
    if (i == n) rp[n] = E;
}

// CSR fill: epack[idx] = {src, bits(dinv[d]*dinv[s])}
__global__ void k_fill(const int* __restrict__ src, const int* __restrict__ dst,
                       const int* __restrict__ rp, int* __restrict__ cursor,
                       int2* __restrict__ epack, const float* __restrict__ dinv, int E) {
    int i = blockIdx.x * blockDim.x + threadIdx.x;
    if (i < E) {
        int d = dst[i], s = src[i];
        int p = atomicAdd(&cursor[d], 1);
        int2 r; r.x = s; r.y = __float_as_int(dinv[d] * dinv[s]);
        epack[rp[d] + p] = r;
    }
}

// ---------------------------------------------------------------------------
// XCD-sliced gather core: slice f = blockIdx&7 (round-robin -> XCD f keeps its
// 3.2MB feature slice L2-resident). Wave = 32 records x 2 lanes (16B each);
// one uint4 gather instruction covers 32 edge rows. Edge records nt-loaded
// (8B, no L2 pollution). 8 nodes per wave. 5-round butterfly reduce.
#define AGGS_CORE(X)                                                             \
    int lane = threadIdx.x & 63;                                                 \
    int wv   = threadIdx.x >> 6;                                                 \
    int f    = blockIdx.x & 7;                                                   \
    int vb   = (blockIdx.x >> 3) * 32 + wv * 8;                                  \
    int half = lane & 1, ri = lane >> 1;                                         \
    (void)f;                                                                     \
    for (int n = 0; n < 8; ++n) {                                                \
        int v = vb + n;                                                          \
        float dv = dinv[v];                                                      \
        int e0 = rp[v], L = rp[v + 1] - e0 + 1;                                  \
        float acc[8] = {0.f,0.f,0.f,0.f,0.f,0.f,0.f,0.f};                        \
        for (int b = ri; b < L; b += 32) {                                       \
            int s; float w;                                                      \
            if (b == 0) { s = v; w = dv * dv; }                                  \
            else {                                                               \
                int2v r = __builtin_nontemporal_load(                            \
                              (const int2v*)(epack + e0 + b - 1));               \
                s = r.x; w = __int_as_float(r.y);                                \
            }                                                                    \
            uint4v u = *(const uint4v*)(X + (size_t)s * 8 + half * 4);           \
            fma8(acc, w, u);                                                     \
        }                                                                        \
        _Pragma("unroll")                                                        \
        for (int j = 0; j < 8; ++j) {                                            \
            acc[j] += __shfl_xor(acc[j], 2, 64);                                 \
            acc[j] += __shfl_xor(acc[j], 4, 64);                                 \
            acc[j] += __shfl_xor(acc[j], 8, 64);                                 \
            acc[j] += __shfl_xor(acc[j], 16, 64);                                \
            acc[j] += __shfl_xor(acc[j], 32, 64);                                \
        }

// layer 1: output sliced bf16 A
__global__ __launch_bounds__(256) void k_aggA(
    const unsigned* __restrict__ Xs, unsigned* __restrict__ Os,
    const int* __restrict__ rp, const int2* __restrict__ epack,
    const float* __restrict__ dinv)
{
    const unsigned* X = Xs + (size_t)(blockIdx.x & 7) * SLICE_U;
    unsigned* O       = Os + (size_t)(blockIdx.x & 7) * SLICE_U;
    AGGS_CORE(X)
        if (ri == 0) {
            uint4v o;
            o.x = packbf2(acc[0], acc[1]);
            o.y = packbf2(acc[2], acc[3]);
            o.z = packbf2(acc[4], acc[5]);
            o.w = packbf2(acc[6], acc[7]);
            __builtin_nontemporal_store(o, (uint4v*)(O + (size_t)v * 8 + half * 4));
        }
    }
}

// layer 2: output dense f32 Q rows (consumed by the fused pool+classifier)
__global__ __launch_bounds__(256) void k_aggQ(
    const unsigned* __restrict__ Xs, float* __restrict__ Q,
    const int* __restrict__ rp, const int2* __restrict__ epack,
    const float* __restrict__ dinv)
{
    const unsigned* X = Xs + (size_t)(blockIdx.x & 7) * SLICE_U;
    AGGS_CORE(X)
        if (ri == 0) {
            f32x4 q0 = {acc[0], acc[1], acc[2], acc[3]};
            f32x4 q1 = {acc[4], acc[5], acc[6], acc[7]};
            float* qp = Q + (size_t)v * FDIM + f * 16 + half * 8;
            __builtin_nontemporal_store(q0, (f32x4*)qp);
            __builtin_nontemporal_store(q1, (f32x4*)(qp + 4));
        }
    }
}

// ---------------------------------------------------------------------------
// B = relu(A @ W1 + b1), A sliced bf16 in, B sliced bf16 out (nt), MFMA
__global__ __launch_bounds__(256) void k_gemm_mfma(
    const unsigned short* __restrict__ A, const unsigned short* __restrict__ Wt,
    const float* __restrict__ bias, unsigned short* __restrict__ B)
{
    int lane = threadIdx.x & 63;
    int wv = threadIdx.x >> 6;
    size_t row0 = (size_t)blockIdx.x * 64 + (size_t)wv * 16;
    int r = lane & 15, g = lane >> 4;

    short8v af[4];
#pragma unroll
    for (int ks = 0; ks < 4; ++ks) {
        int fa  = 2 * ks + (g >> 1);          // slice of features ks*32 + g*8
        int off = (g & 1) * 8;
        af[ks] = *(const short8v*)(A + (size_t)fa * SLICE_U * 2 + (row0 + r) * 16 + off);
    }

    f32x4 acc[8];
#pragma unroll
    for (int ct = 0; ct < 8; ++ct) {
        f32x4 a = {0.f, 0.f, 0.f, 0.f};
        const unsigned short* wrow = Wt + (ct * 16 + r) * FDIM + g * 8;
#pragma unroll
        for (int ks = 0; ks < 4; ++ks) {
            short8v bfr = *(const short8v*)(wrow + ks * 32);
            a = __builtin_amdgcn_mfma_f32_16x16x32_bf16(af[ks], bfr, a, 0, 0, 0);
        }
        acc[ct] = a;
    }

#pragma unroll
    for (int ct = 0; ct < 8; ++ct) {
        float bs = bias[ct * 16 + r];
#pragma unroll
        for (int i = 0; i < 4; ++i) {
            size_t row = row0 + g * 4 + i;
            if (row < N_NODES) {
                float vv = fmaxf(acc[ct][i] + bs, 0.f);
                __builtin_nontemporal_store(f2bf(vv),
                    B + (size_t)ct * SLICE_U * 2 + row * 16 + r);
            }
        }
    }
}

// ---------------------------------------------------------------------------
__global__ void k_wcomb(const float* __restrict__ W2, const float* __restrict__ Wf,
                        const float* __restrict__ b2, const float* __restrict__ bf,
                        float* __restrict__ Wc, float* __restrict__ bc) {
    int idx = blockIdx.x * blockDim.x + threadIdx.x;
    if (idx < 128 * 32) {
        int k = idx >> 5, c = idx & 31;
        float acc = 0.0f;
        for (int m = 0; m < 128; ++m) acc += W2[k * 128 + m] * Wf[m * 32 + c];
        Wc[idx] = acc;
    }
    if (idx < 32) {
        float acc = bf[idx];
        for (int m = 0; m < 128; ++m) acc += b2[m] * Wf[m * 32 + idx];
        bc[idx] = acc;
    }
}

// fused pool + classifier: per graph, stream contiguous Q rows (batch sorted),
// mean, then fold through Wc. Zero atomics.
__global__ __launch_bounds__(128) void k_final(
    const float* __restrict__ Q, const int* __restrict__ cnt,
    const int* __restrict__ r0, const int* __restrict__ r1,
    const float* __restrict__ Wc, const float* __restrict__ bc,
    const float* __restrict__ bf, float* __restrict__ out)
{
    __shared__ float p[128];
    int g = blockIdx.x, t = threadIdx.x;
    int c_ = cnt[g];
    int v0 = r0[g], v1 = r1[g];
    float s0 = 0.f, s1 = 0.f;
    int v = v0;
    for (; v + 1 < v1; v += 2) {
        s0 += Q[(size_t)v * FDIM + t];
        s1 += Q[(size_t)(v + 1) * FDIM + t];
    }
    if (v < v1) s0 += Q[(size_t)v * FDIM + t];
    float inv = (c_ > 0) ? 1.0f / (float)c_ : 0.0f;
    p[t] = (s0 + s1) * inv;
    __syncthreads();
    if (t < N_CLASSES) {
        float acc = (c_ > 0) ? bc[t] : bf[t];
#pragma unroll
        for (int k = 0; k < 128; ++k) acc = fmaf(p[k], Wc[k * 32 + t], acc);
        out[(size_t)g * N_CLASSES + t] = acc;
    }
}

// ---------------------------------------------------------------------------
extern "C" void kernel_launch(void* const* d_in, const int* in_sizes, int n_in,
                              void* d_out, int out_size, void* d_ws, size_t ws_size,
                              hipStream_t stream) {
    const float* x    = (const float*)d_in[0];
    const int*   ei   = (const int*)d_in[1];
    const int*   batch= (const int*)d_in[2];
    const float* W1   = (const float*)d_in[3];
    const float* b1   = (const float*)d_in[4];
    const float* W2   = (const float*)d_in[5];
    const float* b2   = (const float*)d_in[6];
    const float* Wf   = (const float*)d_in[7];
    const float* bf   = (const float*)d_in[8];
    const int* src = ei;
    const int* dst = ei + N_EDGES;

    char* w = (char*)d_ws;
    auto alloc = [&](size_t bytes) { char* p = w; w += (bytes + 255) & ~255ull; return p; };
    int*      indeg  = (int*)     alloc((size_t)N_NODES * 4);
    float*    dinv   = (float*)   alloc((size_t)N_NODES * 4);
    int*      rp     = (int*)     alloc((size_t)(N_NODES + 1) * 4);
    int*      cursor = (int*)     alloc((size_t)N_NODES * 4);
    int*      bsums  = (int*)     alloc(1024 * 4);
    int2*     epack  = (int2*)    alloc((size_t)N_EDGES * 8);
    unsigned* xh     = (unsigned*)alloc((size_t)SLICE_U * 8 * 4);   // sliced bf16x2
    unsigned* Ab     = (unsigned*)alloc((size_t)SLICE_U * 8 * 4);   // sliced bf16x2
    unsigned* Bb     = (unsigned*)alloc((size_t)SLICE_U * 8 * 4);   // sliced bf16x2
    unsigned short* Wt = (unsigned short*)alloc(128 * 128 * 2);
    int*      cnt    = (int*)     alloc((size_t)N_GRAPHS * 4);
    int*      r0     = (int*)     alloc((size_t)N_GRAPHS * 4);
    int*      r1     = (int*)     alloc((size_t)N_GRAPHS * 4);
    float*    Wc     = (float*)   alloc(128 * 32 * 4);
    float*    bc     = (float*)   alloc(32 * 4);
    // Q (dense f32 [M_PAD][128], 51.2MB) aliases xh+Ab (both dead after GEMM;
    // the two sliced buffers are contiguous and exactly sized M_PAD*128*4)
    float*    Q      = (float*)xh;

    hipMemsetAsync(indeg,  0,    (size_t)N_NODES * 4, stream);
    hipMemsetAsync(cursor, 0,    (size_t)N_NODES * 4, stream);
    hipMemsetAsync(cnt,    0,    (size_t)N_GRAPHS * 4, stream);
    hipMemsetAsync(r0,     0x7f, (size_t)N_GRAPHS * 4, stream);
    hipMemsetAsync(r1,     0,    (size_t)N_GRAPHS * 4, stream);

    const int nbScan = (N_NODES + SCAN_BLK - 1) / SCAN_BLK;   // 98

    // input conversions
    k_f2bf<<<(N_NODES * 64 + 255) / 256, 256, 0, stream>>>(x, xh, N_NODES * 64);
    k_wt  <<<64, 256, 0, stream>>>(W1, Wt);

    // degrees, dinv, per-graph meta
    k_count<<<(N_EDGES + 255) / 256, 256, 0, stream>>>(dst, indeg, N_EDGES);
    k_prep <<<(N_NODES + 255) / 256, 256, 0, stream>>>(indeg, dinv, batch, cnt, r0, r1, N_NODES);

    // CSR scan + fill
    k_scan1<<<nbScan, 256, 0, stream>>>(indeg, rp, bsums, N_NODES);
    k_scan2<<<1, 256, 0, stream>>>(bsums, nbScan);
    k_scan3<<<(N_NODES + 1 + 255) / 256, 256, 0, stream>>>(rp, bsums, N_NODES, N_EDGES);
    k_fill <<<(N_EDGES + 255) / 256, 256, 0, stream>>>(src, dst, rp, cursor, epack, dinv, N_EDGES);

    // layer 1: sliced gather -> MFMA GEMM (+bias+relu)
    k_aggA<<<(N_NODES / 32) * 8, 256, 0, stream>>>(xh, Ab, rp, epack, dinv);
    k_gemm_mfma<<<M_PAD / 64, 256, 0, stream>>>((const unsigned short*)Ab, Wt, b1,
                                                (unsigned short*)Bb);

    // classifier weight folding (tiny, independent)
    k_wcomb<<<16, 256, 0, stream>>>(W2, Wf, b2, bf, Wc, bc);

    // layer 2: sliced gather -> dense f32 Q rows (aliases xh/Ab)
    k_aggQ<<<(N_NODES / 32) * 8, 256, 0, stream>>>(Bb, Q, rp, epack, dinv);

    // fused mean-pool + classifier
    k_final<<<N_GRAPHS, 128, 0, stream>>>(Q, cnt, r0, r1, Wc, bc, bf, (float*)d_out);
}